// Round 19
// baseline (91.833 us; speedup 1.0000x reference)
//
#include <hip/hip_runtime.h>
#include <hip/hip_bf16.h>
#include <math.h>

typedef __bf16 bf16_t;
typedef __bf16 bf16x8 __attribute__((ext_vector_type(8)));
typedef float floatx4 __attribute__((ext_vector_type(4)));
typedef unsigned int u32;
typedef unsigned short u16;

#define NHEAD 16

// async global->LDS, 16B per lane. Dest must be wave-uniform base + lane*16.
__device__ __forceinline__ void gload_lds16(const void* g, void* l) {
    __builtin_amdgcn_global_load_lds((const __attribute__((address_space(1))) u32*)g,
                                     (__attribute__((address_space(3))) u32*)l, 16, 0, 0);
}

__device__ __forceinline__ bf16x8 cvt8(float4 a, float4 b) {
    bf16x8 o;
    o[0]=(bf16_t)a.x; o[1]=(bf16_t)a.y; o[2]=(bf16_t)a.z; o[3]=(bf16_t)a.w;
    o[4]=(bf16_t)b.x; o[5]=(bf16_t)b.y; o[6]=(bf16_t)b.z; o[7]=(bf16_t)b.w;
    return o;
}

// ---------------- prep: Wq/Wk/Wv fp32->bf16 + RoPE table (Wo folded into o-gemm) ----------------
__global__ __launch_bounds__(256) void k_prep(
    const float* __restrict__ wq, const float* __restrict__ wk,
    const float* __restrict__ wv,
    bf16_t* __restrict__ Wqb, bf16_t* __restrict__ Wkb, bf16_t* __restrict__ Wvb,
    float* __restrict__ ct, float* __restrict__ st)
{
    int b = blockIdx.x;
    if (b < 1536) {
        const float* src; bf16_t* dst; int off;
        if      (b < 512)  { src = wq; dst = Wqb; off = b; }
        else if (b < 1024) { src = wk; dst = Wkb; off = b - 512; }
        else               { src = wv; dst = Wvb; off = b - 1024; }
        int i = (off * 256 + threadIdx.x) * 8;
        float4 a = *(const float4*)(src + i);
        float4 c = *(const float4*)(src + i + 4);
        *(bf16x8*)(dst + i) = cvt8(a, c);
    } else {
        int idx = (b - 1536) * 256 + threadIdx.x;   // 65536 = 2048*32
        int s = idx >> 5, i = idx & 31;
        float e = (float)(2 * i) / 64.0f;
        float invf = 1.0f / powf(10000.0f, e);
        float ang = (float)s * invf;
        ct[idx] = cosf(ang);
        st[idx] = sinf(ang);
    }
}

// ---------------- QKV GEMM: 128x128, BK=32, 2-buf __syncthreads (R11/R17/R18 proven). ----------------
// A staged as fp32 via gload_lds into [128][32]f tile (128B rows, (row&7)<<4 XOR:
// coalesced stage, bank-spread b128 reads), cvt to bf16 in-reg. No X prep pass.
__global__ __launch_bounds__(256,3) void k_gemm_qkv(
    const float* __restrict__ Xq, const float* __restrict__ Xk, const float* __restrict__ Xv,
    const bf16_t* __restrict__ Wqb, const bf16_t* __restrict__ Wkb, const bf16_t* __restrict__ Wvb,
    const float* __restrict__ bq, const float* __restrict__ bk, const float* __restrict__ bv,
    bf16_t* __restrict__ Qr, bf16_t* __restrict__ Kr, bf16_t* __restrict__ Vh,
    const float* __restrict__ ct, const float* __restrict__ st)
{
    __shared__ __align__(16) float  As[2][4096];   // [128 rows][32 k] fp32, 16KB per buf
    __shared__ __align__(16) bf16_t Bs[2][4096];   // [128 rows][32 k] bf16, 8KB per buf

    // XCD swizzle: 768 logical wgs, 96-chunk per XCD
    int b0 = blockIdx.x;
    int wg = (b0 & 7) * 96 + (b0 >> 3);
    int id  = wg >> 8;                  // 0=Q 1=K 2=V
    int bid = wg & 255;

    const float*  A   = (id==0) ? Xq  : (id==1) ? Xk  : Xv;
    const bf16_t* Wt  = (id==0) ? Wqb : (id==1) ? Wkb : Wvb;
    const float*  bias= (id==0) ? bq  : (id==1) ? bk  : bv;
    bf16_t* out = (id==0) ? Qr : (id==1) ? Kr : Vh;
    bool do_rope = (id < 2);

    int bm = (bid >> 3) << 7;           // M=4096 -> 32 row tiles
    int bn = (bid & 7) << 7;            // N=1024 -> 8 col tiles
    int tid = threadIdx.x;
    int l = tid & 63, wid = tid >> 6;
    int wr = wid >> 1, wc = wid & 1;
    int fr = l & 15, kg = l >> 4;

    floatx4 acc[4][4];
    #pragma unroll
    for (int i = 0; i < 4; ++i)
        #pragma unroll
        for (int j = 0; j < 4; ++j) acc[i][j] = (floatx4){0.f,0.f,0.f,0.f};

    // A staging: 1024 16B-chunks; chunk c -> row c>>3, in-row byte ((c&7)<<4)^((row&7)<<4)
    const char* ApB[4];
    #pragma unroll
    for (int it = 0; it < 4; ++it) {
        int c = tid + (it << 8);
        int row = c >> 3;
        int zp = ((c & 7) << 4) ^ ((row & 7) << 4);
        ApB[it] = (const char*)A + ((size_t)(bm + row) << 12) + zp;
    }
    // B staging: 2 chunks/thread, rows tid>>2 and +64
    int srowB = tid >> 2, scolB = (tid & 3) << 3;
    const bf16_t* Bp0 = Wt + ((size_t)(bn + srowB) << 10) + scolB;
    const bf16_t* Bp1 = Wt + ((size_t)(bn + 64 + srowB) << 10) + scolB;

    // prologue: stage tile 0 -> buf 0
    #pragma unroll
    for (int it = 0; it < 4; ++it)
        gload_lds16(ApB[it], (char*)As[0] + ((tid + (it << 8)) << 4));
    gload_lds16(Bp0, &Bs[0][tid << 3]);
    gload_lds16(Bp1, &Bs[0][(tid + 256) << 3]);
    __syncthreads();

    int swA = (fr & 7) << 4;
    int cur = 0;
    for (int t = 0; t < 32; ++t) {
        if (t < 31) {                   // prefetch tile t+1 (in flight across MFMA phase)
            int kA = (t + 1) << 7;      // byte offset in A row (32 floats)
            int kB = (t + 1) << 5;      // elem offset in B row
            #pragma unroll
            for (int it = 0; it < 4; ++it)
                gload_lds16(ApB[it] + kA, (char*)As[cur ^ 1] + ((tid + (it << 8)) << 4));
            gload_lds16(Bp0 + kB, &Bs[cur ^ 1][tid << 3]);
            gload_lds16(Bp1 + kB, &Bs[cur ^ 1][(tid + 256) << 3]);
        }
        const char* Ac = (const char*)As[cur];
        bf16x8 af[4], bfr[4];
        #pragma unroll
        for (int i = 0; i < 4; ++i) {
            int rowbyte = ((wr << 6) + (i << 4) + fr) << 7;
            float4 lo = *(const float4*)(Ac + rowbyte + ((kg << 5) ^ swA));
            float4 hi = *(const float4*)(Ac + rowbyte + (((kg << 5) + 16) ^ swA));
            af[i] = cvt8(lo, hi);
        }
        #pragma unroll
        for (int j = 0; j < 4; ++j)
            bfr[j] = *(const bf16x8*)&Bs[cur][((wc << 6) + (j << 4) + fr) * 32 + (kg << 3)];
        #pragma unroll
        for (int i = 0; i < 4; ++i)
            #pragma unroll
            for (int j = 0; j < 4; ++j)
                acc[i][j] = __builtin_amdgcn_mfma_f32_16x16x32_bf16(af[i], bfr[j], acc[i][j], 0, 0, 0);
        __syncthreads();                // drains after compute; prefetch had MFMA phase to land
        cur ^= 1;
    }

    int h = (bn + (wc<<6)) >> 6;        // head index (64-wide wave tile == one head)
    #pragma unroll
    for (int i = 0; i < 4; ++i) {
        #pragma unroll
        for (int r = 0; r < 4; ++r) {
            int m  = bm + (wr<<6) + (i<<4) + (kg<<2) + r;
            int b_ = m >> 11, s_ = m & 2047;
            size_t ob = ((((size_t)(b_*NHEAD + h)) << 11) + s_) << 6;
            if (do_rope) {
                #pragma unroll
                for (int j = 0; j < 2; ++j) {
                    int d = (j<<4) + fr;                     // 0..31
                    float lo = acc[i][j][r]   + bias[bn + (wc<<6) + d];
                    float hv = acc[i][j+2][r] + bias[bn + (wc<<6) + d + 32];
                    float c = ct[(s_<<5) + d], sn = st[(s_<<5) + d];
                    out[ob + d]      = (bf16_t)(lo*c - hv*sn);
                    out[ob + d + 32] = (bf16_t)(hv*c + lo*sn);
                }
            } else {
                #pragma unroll
                for (int j = 0; j < 4; ++j) {
                    int d = (j<<4) + fr;
                    out[ob + d] = (bf16_t)(acc[i][j][r] + bias[bn + (wc<<6) + d]);
                }
            }
        }
    }
}

// ---------------- O GEMM: 64x64 tile, BK=32, 2-buf __syncthreads. ----------------
// NEW: Wo read as fp32 directly (B staged fp32, qkv-A-proven pattern), deletes prep Wo leg.
__global__ __launch_bounds__(256,4) void k_gemm_o(
    const bf16_t* __restrict__ A, const float* __restrict__ Wo,
    const float* __restrict__ bias, float* __restrict__ out)
{
    __shared__ __align__(16) bf16_t As[2][2048];   // [64][32] bf16, 4KB per buf
    __shared__ __align__(16) float  Bf[2][2048];   // [64][32] fp32, 8KB per buf

    int b0 = blockIdx.x;
    int wg = (b0 & 7) * 128 + (b0 >> 3);   // 1024 wgs, 128 per XCD
    int bm = (wg >> 4) << 6;               // 64 row-tiles
    int bn = (wg & 15) << 6;               // 16 col-tiles
    int tid = threadIdx.x;
    int l = tid & 63, wid = tid >> 6;
    int fr = l & 15, kg = l >> 4;

    floatx4 acc[4];
    #pragma unroll
    for (int j = 0; j < 4; ++j) acc[j] = (floatx4){0.f,0.f,0.f,0.f};

    // A staging (bf16, proven): chunk tid -> row tid>>2, XOR-permuted slot
    int srow = tid >> 2;
    int scol = ((tid & 3) ^ (srow & 3)) << 3;
    const bf16_t* Ap = A + ((size_t)(bm + srow) << 10) + scol;
    // B staging (fp32, qkv-A pattern): 512 chunks, 2/thread; chunk c -> row c>>3,
    // in-row byte ((c&7)<<4)^((row&7)<<4); wave = 8 rows x full 128B (coalesced)
    const char* BpB[2];
    #pragma unroll
    for (int it = 0; it < 2; ++it) {
        int c = tid + (it << 8);
        int row = c >> 3;
        int zp = ((c & 7) << 4) ^ ((row & 7) << 4);
        BpB[it] = (const char*)Wo + ((size_t)(bn + row) << 12) + zp;
    }

    gload_lds16(Ap, &As[0][tid << 3]);
    #pragma unroll
    for (int it = 0; it < 2; ++it)
        gload_lds16(BpB[it], (char*)Bf[0] + ((tid + (it << 8)) << 4));
    __syncthreads();

    int a_off = fr * 64 + ((kg ^ (fr & 3)) << 4);
    int swB = (fr & 7) << 4;
    int cur = 0;
    for (int t = 0; t < 32; ++t) {
        if (t < 31) {
            int kA = (t + 1) << 5;      // elem offset in A row
            int kB = (t + 1) << 7;      // byte offset in Wo row (32 floats)
            gload_lds16(Ap + kA, &As[cur ^ 1][tid << 3]);
            #pragma unroll
            for (int it = 0; it < 2; ++it)
                gload_lds16(BpB[it] + kB, (char*)Bf[cur ^ 1] + ((tid + (it << 8)) << 4));
        }
        const char* Bc = (const char*)Bf[cur];
        bf16x8 af, bfr[4];
        af = *(const bf16x8*)((const char*)As[cur] + (wid << 10) + a_off);
        #pragma unroll
        for (int j = 0; j < 4; ++j) {
            int rowbyte = ((j << 4) + fr) << 7;
            float4 lo = *(const float4*)(Bc + rowbyte + ((kg << 5) ^ swB));
            float4 hi = *(const float4*)(Bc + rowbyte + (((kg << 5) + 16) ^ swB));
            bfr[j] = cvt8(lo, hi);
        }
        #pragma unroll
        for (int j = 0; j < 4; ++j)
            acc[j] = __builtin_amdgcn_mfma_f32_16x16x32_bf16(af, bfr[j], acc[j], 0, 0, 0);
        __syncthreads();
        cur ^= 1;
    }

    #pragma unroll
    for (int r = 0; r < 4; ++r) {
        int m = bm + (wid << 4) + (kg << 2) + r;
        #pragma unroll
        for (int j = 0; j < 4; ++j) {
            int n = bn + (j << 4) + fr;
            out[((size_t)m << 10) + n] = acc[j][r] + bias[n];
        }
    }
}

// ---------------- sliding-window attention (R18 proven: flat grid + XCD swizzle) ----------------
__global__ __launch_bounds__(256,3) void k_attn(
    const bf16_t* __restrict__ Qr, const bf16_t* __restrict__ Kr,
    const bf16_t* __restrict__ Vh, bf16_t* __restrict__ AO)
{
    __shared__ char smem[51200];
    char* KsPs = smem;                        // K window (swizzled), later aliased by P
    char* VtB  = smem + 25600;                // V^T [64 d][200 keys-stride] bytes, swizzled

    // bijective XCD swizzle: 1024 = 8 XCD x 128; each XCD gets 4 heads x 32 q-blocks
    int wg = (blockIdx.x & 7) * 128 + (blockIdx.x >> 3);
    int b_ = wg >> 9;                         // batch (2)
    int h  = (wg >> 5) & 15;                  // head (16)
    int q0 = (wg & 31) << 6;                  // q-block (32)

    int kstart = q0 - 64; if (kstart < 0) kstart = 0;
    int kend   = q0 + 128; if (kend > 2048) kend = 2048;
    int NR = kend - kstart;                   // 128 or 192

    int tid = threadIdx.x, l = tid & 63, w = tid >> 6;
    int lane16 = l & 15, hi8 = (l >> 4) << 3;

    const bf16_t* Kbase = Kr + (((((size_t)(b_*NHEAD + h)) << 11) + kstart) << 6);
    const bf16_t* Vbase = Vh + (((((size_t)(b_*NHEAD + h)) << 11) + kstart) << 6);

    // K stage (rule #21: linear dest, pre-swizzled source; read applies same XOR)
    #pragma unroll
    for (int it = 0; it < 6; ++it) {
        int c = tid + (it << 8);
        int y = c << 4;                       // dest byte, 192 rows * 128B
        int row = y >> 7, oz = y & 127;
        int srw = row < NR ? row : NR - 1;
        int src = (srw << 7) + (oz ^ ((row & 7) << 4));
        gload_lds16((const char*)Kbase + src, KsPs + y);
    }
    // V^T stage: key-pair u32 writes
    #pragma unroll
    for (int it = 0; it < 6; ++it) {
        int c = tid + (it << 8);              // 1536 chunks: 96 key-pairs x 16 d-quads
        int jd2 = c >> 4;                     // key-pair index
        int dq  = (c & 15) << 2;              // d0 of quad
        int j0 = jd2 << 1, j1 = j0 + 1;
        int j0c = j0 < NR ? j0 : NR - 1;
        int j1c = j1 < NR ? j1 : NR - 1;
        ushort4 v0 = *(const ushort4*)(Vbase + (j0c << 6) + dq);
        ushort4 v1 = *(const ushort4*)(Vbase + (j1c << 6) + dq);
        u16 a0[4] = {(u16)v0.x,(u16)v0.y,(u16)v0.z,(u16)v0.w};
        u16 a1[4] = {(u16)v1.x,(u16)v1.y,(u16)v1.z,(u16)v1.w};
        #pragma unroll
        for (int t = 0; t < 4; ++t) {
            int d = dq + t;
            u32 pair = (u32)a0[t] | ((u32)a1[t] << 16);
            *(u32*)(VtB + d * 400 + ((jd2 << 2) ^ (((d >> 3) & 7) << 4))) = pair;
        }
    }
    int qs = q0 + (w << 4) + lane16;
    const bf16_t* Qbase = Qr + (((((size_t)(b_*NHEAD + h)) << 11) + qs) << 6);
    bf16x8 qf0 = *(const bf16x8*)(Qbase + hi8);
    bf16x8 qf1 = *(const bf16x8*)(Qbase + 32 + hi8);

    __syncthreads();

    floatx4 sc[12];
    #pragma unroll
    for (int kt = 0; kt < 12; ++kt) {
        int row = (kt << 4) + lane16;
        int base = (row << 7) + (hi8 << 1);
        int swz = (row & 7) << 4;
        bf16x8 kf0 = *(const bf16x8*)(KsPs + (base ^ swz));
        bf16x8 kf1 = *(const bf16x8*)(KsPs + ((base + 64) ^ swz));
        floatx4 a = (floatx4){0.f,0.f,0.f,0.f};
        a = __builtin_amdgcn_mfma_f32_16x16x32_bf16(qf0, kf0, a, 0, 0, 0);
        a = __builtin_amdgcn_mfma_f32_16x16x32_bf16(qf1, kf1, a, 0, 0, 0);
        sc[kt] = a;
    }

    float inv_[4];
    #pragma unroll
    for (int r = 0; r < 4; ++r) {
        int qrow = q0 + (w << 4) + ((l >> 4) << 2) + r;
        float mx = -1e30f;
        #pragma unroll
        for (int kt = 0; kt < 12; ++kt) {
            int ks = kstart + (kt << 4) + lane16;
            int dd = qrow - ks; dd = dd < 0 ? -dd : dd;
            float sv = sc[kt][r] * 0.125f;
            sv = (dd <= 50 && ks < kend) ? sv : -1e30f;
            sc[kt][r] = sv;
            mx = fmaxf(mx, sv);
        }
        #pragma unroll
        for (int off = 1; off < 16; off <<= 1) mx = fmaxf(mx, __shfl_xor(mx, off));
        float sum = 0.f;
        #pragma unroll
        for (int kt = 0; kt < 12; ++kt) {
            float p = __expf(sc[kt][r] - mx);
            sc[kt][r] = p;
            sum += p;
        }
        #pragma unroll
        for (int off = 1; off < 16; off <<= 1) sum += __shfl_xor(sum, off);
        inv_[r] = 1.0f / sum;
    }

    __syncthreads();   // all waves done reading K window -> P may overwrite it

    // P -> per-wave LDS, swizzled writes
    char* PwB = KsPs + w * 6400;
    #pragma unroll
    for (int r = 0; r < 4; ++r) {
        int prow = ((l >> 4) << 2) + r;
        int pm = ((prow >> 2) & 3) << 4;
        #pragma unroll
        for (int kt = 0; kt < 12; ++kt) {
            int keyoff = ((kt << 4) + lane16) << 1;
            *(bf16_t*)(PwB + prow * 400 + (keyoff ^ pm)) = (bf16_t)(sc[kt][r] * inv_[r]);
        }
    }

    floatx4 oc[4];
    #pragma unroll
    for (int dt = 0; dt < 4; ++dt) oc[dt] = (floatx4){0.f,0.f,0.f,0.f};
    int pm_r = ((lane16 >> 2) & 3) << 4;
    #pragma unroll
    for (int ks = 0; ks < 6; ++ks) {
        int keyoff = ((ks << 5) + hi8) << 1;
        bf16x8 pf = *(const bf16x8*)(PwB + lane16 * 400 + (keyoff ^ pm_r));
        #pragma unroll
        for (int dt = 0; dt < 4; ++dt) {
            int d = (dt << 4) + lane16;
            bf16x8 vf = *(const bf16x8*)(VtB + d * 400 + (keyoff ^ (((d >> 3) & 7) << 4)));
            oc[dt] = __builtin_amdgcn_mfma_f32_16x16x32_bf16(pf, vf, oc[dt], 0, 0, 0);
        }
    }
    #pragma unroll
    for (int dt = 0; dt < 4; ++dt)
        #pragma unroll
        for (int r = 0; r < 4; ++r) {
            int qq = q0 + (w << 4) + ((l >> 4) << 2) + r;
            AO[(((size_t)(b_ * 2048 + qq)) << 10) + (h << 6) + (dt << 4) + lane16] = (bf16_t)oc[dt][r];
        }
}

extern "C" void kernel_launch(void* const* d_in, const int* in_sizes, int n_in,
                              void* d_out, int out_size, void* d_ws, size_t ws_size,
                              hipStream_t stream)
{
    const float* query = (const float*)d_in[0];
    const float* key_  = (const float*)d_in[1];
    const float* value = (const float*)d_in[2];
    const float* Wq = (const float*)d_in[3];
    const float* bq = (const float*)d_in[4];
    const float* Wk = (const float*)d_in[5];
    const float* bk = (const float*)d_in[6];
    const float* Wv = (const float*)d_in[7];
    const float* bv = (const float*)d_in[8];
    const float* Wo = (const float*)d_in[9];
    const float* bo = (const float*)d_in[10];

    char* ws = (char*)d_ws;
    bf16_t* Wqb = (bf16_t*)(ws);
    bf16_t* Wkb = (bf16_t*)(ws + 2097152);
    bf16_t* Wvb = (bf16_t*)(ws + 4194304);
    bf16_t* Qr  = (bf16_t*)(ws + 8388608);
    bf16_t* Kr  = (bf16_t*)(ws + 16777216);
    bf16_t* Vh  = (bf16_t*)(ws + 25165824);
    bf16_t* AO  = (bf16_t*)(ws + 33554432);
    float*  ct  = (float*)(ws + 41943040);
    float*  st  = (float*)(ws + 42205184);

    k_prep<<<1792, 256, 0, stream>>>(Wq, Wk, Wv, Wqb, Wkb, Wvb, ct, st);
    k_gemm_qkv<<<768, 256, 0, stream>>>(query, key_, value, Wqb, Wkb, Wvb,
                                        bq, bk, bv, Qr, Kr, Vh, ct, st);
    k_attn<<<1024, 256, 0, stream>>>(Qr, Kr, Vh, AO);
    k_gemm_o<<<1024, 256, 0, stream>>>(AO, Wo, bo, (float*)d_out);
}

// Round 20
// 90.403 us; speedup vs baseline: 1.0158x; 1.0158x over previous
//
#include <hip/hip_runtime.h>
#include <hip/hip_bf16.h>
#include <math.h>

typedef __bf16 bf16_t;
typedef __bf16 bf16x8 __attribute__((ext_vector_type(8)));
typedef float floatx4 __attribute__((ext_vector_type(4)));
typedef unsigned int u32;
typedef unsigned short u16;

#define NHEAD 16

// async global->LDS, 16B per lane. Dest must be wave-uniform base + lane*16.
__device__ __forceinline__ void gload_lds16(const void* g, void* l) {
    __builtin_amdgcn_global_load_lds((const __attribute__((address_space(1))) u32*)g,
                                     (__attribute__((address_space(3))) u32*)l, 16, 0, 0);
}

__device__ __forceinline__ bf16x8 cvt8(float4 a, float4 b) {
    bf16x8 o;
    o[0]=(bf16_t)a.x; o[1]=(bf16_t)a.y; o[2]=(bf16_t)a.z; o[3]=(bf16_t)a.w;
    o[4]=(bf16_t)b.x; o[5]=(bf16_t)b.y; o[6]=(bf16_t)b.z; o[7]=(bf16_t)b.w;
    return o;
}

// ---------------- prep: W fp32->bf16 (4 matrices) + RoPE table ----------------
__global__ __launch_bounds__(256) void k_prep(
    const float* __restrict__ wq, const float* __restrict__ wk,
    const float* __restrict__ wv, const float* __restrict__ wo,
    bf16_t* __restrict__ Wqb, bf16_t* __restrict__ Wkb, bf16_t* __restrict__ Wvb,
    bf16_t* __restrict__ Wob, float* __restrict__ ct, float* __restrict__ st)
{
    int b = blockIdx.x;
    if (b < 2048) {
        const float* src; bf16_t* dst; int off;
        if      (b < 512)  { src = wq; dst = Wqb; off = b; }
        else if (b < 1024) { src = wk; dst = Wkb; off = b - 512; }
        else if (b < 1536) { src = wv; dst = Wvb; off = b - 1024; }
        else               { src = wo; dst = Wob; off = b - 1536; }
        int i = (off * 256 + threadIdx.x) * 8;
        float4 a = *(const float4*)(src + i);
        float4 c = *(const float4*)(src + i + 4);
        *(bf16x8*)(dst + i) = cvt8(a, c);
    } else {
        int idx = (b - 2048) * 256 + threadIdx.x;   // 65536 = 2048*32
        int s = idx >> 5, i = idx & 31;
        float e = (float)(2 * i) / 64.0f;
        float invf = 1.0f / powf(10000.0f, e);
        float ang = (float)s * invf;
        ct[idx] = cosf(ang);
        st[idx] = sinf(ang);
    }
}

// ---------------- QKV GEMM: 128x128, BK=32, 2-buf __syncthreads (R11/R17/R18 proven). ----------------
// A staged as fp32 via gload_lds into [128][32]f tile (128B rows, (row&7)<<4 XOR:
// coalesced stage, bank-spread b128 reads), cvt to bf16 in-reg. No X prep pass.
__global__ __launch_bounds__(256,3) void k_gemm_qkv(
    const float* __restrict__ Xq, const float* __restrict__ Xk, const float* __restrict__ Xv,
    const bf16_t* __restrict__ Wqb, const bf16_t* __restrict__ Wkb, const bf16_t* __restrict__ Wvb,
    const float* __restrict__ bq, const float* __restrict__ bk, const float* __restrict__ bv,
    bf16_t* __restrict__ Qr, bf16_t* __restrict__ Kr, bf16_t* __restrict__ Vh,
    const float* __restrict__ ct, const float* __restrict__ st)
{
    __shared__ __align__(16) float  As[2][4096];   // [128 rows][32 k] fp32, 16KB per buf
    __shared__ __align__(16) bf16_t Bs[2][4096];   // [128 rows][32 k] bf16, 8KB per buf

    // XCD swizzle: 768 logical wgs, 96-chunk per XCD
    int b0 = blockIdx.x;
    int wg = (b0 & 7) * 96 + (b0 >> 3);
    int id  = wg >> 8;                  // 0=Q 1=K 2=V
    int bid = wg & 255;

    const float*  A   = (id==0) ? Xq  : (id==1) ? Xk  : Xv;
    const bf16_t* Wt  = (id==0) ? Wqb : (id==1) ? Wkb : Wvb;
    const float*  bias= (id==0) ? bq  : (id==1) ? bk  : bv;
    bf16_t* out = (id==0) ? Qr : (id==1) ? Kr : Vh;
    bool do_rope = (id < 2);

    int bm = (bid >> 3) << 7;           // M=4096 -> 32 row tiles
    int bn = (bid & 7) << 7;            // N=1024 -> 8 col tiles
    int tid = threadIdx.x;
    int l = tid & 63, wid = tid >> 6;
    int wr = wid >> 1, wc = wid & 1;
    int fr = l & 15, kg = l >> 4;

    floatx4 acc[4][4];
    #pragma unroll
    for (int i = 0; i < 4; ++i)
        #pragma unroll
        for (int j = 0; j < 4; ++j) acc[i][j] = (floatx4){0.f,0.f,0.f,0.f};

    // A staging: 1024 16B-chunks; chunk c -> row c>>3, in-row byte ((c&7)<<4)^((row&7)<<4)
    const char* ApB[4];
    #pragma unroll
    for (int it = 0; it < 4; ++it) {
        int c = tid + (it << 8);
        int row = c >> 3;
        int zp = ((c & 7) << 4) ^ ((row & 7) << 4);
        ApB[it] = (const char*)A + ((size_t)(bm + row) << 12) + zp;
    }
    // B staging: 2 chunks/thread, rows tid>>2 and +64
    int srowB = tid >> 2, scolB = (tid & 3) << 3;
    const bf16_t* Bp0 = Wt + ((size_t)(bn + srowB) << 10) + scolB;
    const bf16_t* Bp1 = Wt + ((size_t)(bn + 64 + srowB) << 10) + scolB;

    // prologue: stage tile 0 -> buf 0
    #pragma unroll
    for (int it = 0; it < 4; ++it)
        gload_lds16(ApB[it], (char*)As[0] + ((tid + (it << 8)) << 4));
    gload_lds16(Bp0, &Bs[0][tid << 3]);
    gload_lds16(Bp1, &Bs[0][(tid + 256) << 3]);
    __syncthreads();

    int swA = (fr & 7) << 4;
    int cur = 0;
    for (int t = 0; t < 32; ++t) {
        if (t < 31) {                   // prefetch tile t+1 (in flight across MFMA phase)
            int kA = (t + 1) << 7;      // byte offset in A row (32 floats)
            int kB = (t + 1) << 5;      // elem offset in B row
            #pragma unroll
            for (int it = 0; it < 4; ++it)
                gload_lds16(ApB[it] + kA, (char*)As[cur ^ 1] + ((tid + (it << 8)) << 4));
            gload_lds16(Bp0 + kB, &Bs[cur ^ 1][tid << 3]);
            gload_lds16(Bp1 + kB, &Bs[cur ^ 1][(tid + 256) << 3]);
        }
        const char* Ac = (const char*)As[cur];
        bf16x8 af[4], bfr[4];
        #pragma unroll
        for (int i = 0; i < 4; ++i) {
            int rowbyte = ((wr << 6) + (i << 4) + fr) << 7;
            float4 lo = *(const float4*)(Ac + rowbyte + ((kg << 5) ^ swA));
            float4 hi = *(const float4*)(Ac + rowbyte + (((kg << 5) + 16) ^ swA));
            af[i] = cvt8(lo, hi);
        }
        #pragma unroll
        for (int j = 0; j < 4; ++j)
            bfr[j] = *(const bf16x8*)&Bs[cur][((wc << 6) + (j << 4) + fr) * 32 + (kg << 3)];
        #pragma unroll
        for (int i = 0; i < 4; ++i)
            #pragma unroll
            for (int j = 0; j < 4; ++j)
                acc[i][j] = __builtin_amdgcn_mfma_f32_16x16x32_bf16(af[i], bfr[j], acc[i][j], 0, 0, 0);
        __syncthreads();                // drains after compute; prefetch had MFMA phase to land
        cur ^= 1;
    }

    int h = (bn + (wc<<6)) >> 6;        // head index (64-wide wave tile == one head)
    #pragma unroll
    for (int i = 0; i < 4; ++i) {
        #pragma unroll
        for (int r = 0; r < 4; ++r) {
            int m  = bm + (wr<<6) + (i<<4) + (kg<<2) + r;
            int b_ = m >> 11, s_ = m & 2047;
            size_t ob = ((((size_t)(b_*NHEAD + h)) << 11) + s_) << 6;
            if (do_rope) {
                #pragma unroll
                for (int j = 0; j < 2; ++j) {
                    int d = (j<<4) + fr;                     // 0..31
                    float lo = acc[i][j][r]   + bias[bn + (wc<<6) + d];
                    float hv = acc[i][j+2][r] + bias[bn + (wc<<6) + d + 32];
                    float c = ct[(s_<<5) + d], sn = st[(s_<<5) + d];
                    out[ob + d]      = (bf16_t)(lo*c - hv*sn);
                    out[ob + d + 32] = (bf16_t)(hv*c + lo*sn);
                }
            } else {
                #pragma unroll
                for (int j = 0; j < 4; ++j) {
                    int d = (j<<4) + fr;
                    out[ob + d] = (bf16_t)(acc[i][j][r] + bias[bn + (wc<<6) + d]);
                }
            }
        }
    }
}

// ---------------- O GEMM: 64x64 tile, BK=32, 2-buf __syncthreads (R10 proven) ----------------
__global__ __launch_bounds__(256,4) void k_gemm_o(
    const bf16_t* __restrict__ A, const bf16_t* __restrict__ Wt,
    const float* __restrict__ bias, float* __restrict__ out)
{
    __shared__ __align__(16) bf16_t As[2][2048];   // [64][32]
    __shared__ __align__(16) bf16_t Bs[2][2048];

    int b0 = blockIdx.x;
    int wg = (b0 & 7) * 128 + (b0 >> 3);   // 1024 wgs, 128 per XCD
    int bm = (wg >> 4) << 6;               // 64 row-tiles
    int bn = (wg & 15) << 6;               // 16 col-tiles
    int tid = threadIdx.x;
    int l = tid & 63, wid = tid >> 6;
    int fr = l & 15, kg = l >> 4;

    floatx4 acc[4];
    #pragma unroll
    for (int j = 0; j < 4; ++j) acc[j] = (floatx4){0.f,0.f,0.f,0.f};

    int srow = tid >> 2;
    int scol = ((tid & 3) ^ (srow & 3)) << 3;
    const bf16_t* Ap = A  + ((size_t)(bm + srow) << 10) + scol;
    const bf16_t* Bp = Wt + ((size_t)(bn + srow) << 10) + scol;

    gload_lds16(Ap, &As[0][tid << 3]);
    gload_lds16(Bp, &Bs[0][tid << 3]);
    __syncthreads();

    int a_off = fr * 64 + ((kg ^ (fr & 3)) << 4);
    int cur = 0;
    for (int t = 0; t < 32; ++t) {
        if (t < 31) {
            int k0 = (t + 1) << 5;
            gload_lds16(Ap + k0, &As[cur ^ 1][tid << 3]);
            gload_lds16(Bp + k0, &Bs[cur ^ 1][tid << 3]);
        }
        bf16x8 af, bfr[4];
        af = *(const bf16x8*)((const char*)As[cur] + (wid << 10) + a_off);
        #pragma unroll
        for (int j = 0; j < 4; ++j)
            bfr[j] = *(const bf16x8*)((const char*)Bs[cur] + (j << 10) + a_off);
        #pragma unroll
        for (int j = 0; j < 4; ++j)
            acc[j] = __builtin_amdgcn_mfma_f32_16x16x32_bf16(af, bfr[j], acc[j], 0, 0, 0);
        __syncthreads();
        cur ^= 1;
    }

    #pragma unroll
    for (int r = 0; r < 4; ++r) {
        int m = bm + (wid << 4) + (kg << 2) + r;
        #pragma unroll
        for (int j = 0; j < 4; ++j) {
            int n = bn + (j << 4) + fr;
            out[((size_t)m << 10) + n] = acc[j][r] + bias[n];
        }
    }
}

// ---------------- sliding-window attention (R18 proven: flat grid + XCD swizzle ----------------
// so each XCD owns 4 complete heads -> consecutive q-blocks of one head (which share
// 2/3 of their K/V window rows) hit the same L2 (T1 regime: inter-block operand reuse).
__global__ __launch_bounds__(256,3) void k_attn(
    const bf16_t* __restrict__ Qr, const bf16_t* __restrict__ Kr,
    const bf16_t* __restrict__ Vh, bf16_t* __restrict__ AO)
{
    __shared__ char smem[51200];
    char* KsPs = smem;                        // K window (swizzled), later aliased by P
    char* VtB  = smem + 25600;                // V^T [64 d][200 keys-stride] bytes, swizzled

    // bijective XCD swizzle: 1024 = 8 XCD x 128; each XCD gets 128 contiguous logical
    // blocks = 4 heads x 32 q-blocks (q-blocks of a head contiguous -> window overlap in L2)
    int wg = (blockIdx.x & 7) * 128 + (blockIdx.x >> 3);
    int b_ = wg >> 9;                         // batch (2)
    int h  = (wg >> 5) & 15;                  // head (16)
    int q0 = (wg & 31) << 6;                  // q-block (32)

    int kstart = q0 - 64; if (kstart < 0) kstart = 0;
    int kend   = q0 + 128; if (kend > 2048) kend = 2048;
    int NR = kend - kstart;                   // 128 or 192

    int tid = threadIdx.x, l = tid & 63, w = tid >> 6;
    int lane16 = l & 15, hi8 = (l >> 4) << 3;

    const bf16_t* Kbase = Kr + (((((size_t)(b_*NHEAD + h)) << 11) + kstart) << 6);
    const bf16_t* Vbase = Vh + (((((size_t)(b_*NHEAD + h)) << 11) + kstart) << 6);

    // K stage (rule #21: linear dest, pre-swizzled source; read applies same XOR)
    #pragma unroll
    for (int it = 0; it < 6; ++it) {
        int c = tid + (it << 8);
        int y = c << 4;                       // dest byte, 192 rows * 128B
        int row = y >> 7, oz = y & 127;
        int srw = row < NR ? row : NR - 1;
        int src = (srw << 7) + (oz ^ ((row & 7) << 4));
        gload_lds16((const char*)Kbase + src, KsPs + y);
    }
    // V^T stage: key-pair u32 writes
    #pragma unroll
    for (int it = 0; it < 6; ++it) {
        int c = tid + (it << 8);              // 1536 chunks: 96 key-pairs x 16 d-quads
        int jd2 = c >> 4;                     // key-pair index
        int dq  = (c & 15) << 2;              // d0 of quad
        int j0 = jd2 << 1, j1 = j0 + 1;
        int j0c = j0 < NR ? j0 : NR - 1;
        int j1c = j1 < NR ? j1 : NR - 1;
        ushort4 v0 = *(const ushort4*)(Vbase + (j0c << 6) + dq);
        ushort4 v1 = *(const ushort4*)(Vbase + (j1c << 6) + dq);
        u16 a0[4] = {(u16)v0.x,(u16)v0.y,(u16)v0.z,(u16)v0.w};
        u16 a1[4] = {(u16)v1.x,(u16)v1.y,(u16)v1.z,(u16)v1.w};
        #pragma unroll
        for (int t = 0; t < 4; ++t) {
            int d = dq + t;
            u32 pair = (u32)a0[t] | ((u32)a1[t] << 16);
            *(u32*)(VtB + d * 400 + ((jd2 << 2) ^ (((d >> 3) & 7) << 4))) = pair;
        }
    }
    int qs = q0 + (w << 4) + lane16;
    const bf16_t* Qbase = Qr + (((((size_t)(b_*NHEAD + h)) << 11) + qs) << 6);
    bf16x8 qf0 = *(const bf16x8*)(Qbase + hi8);
    bf16x8 qf1 = *(const bf16x8*)(Qbase + 32 + hi8);

    __syncthreads();

    floatx4 sc[12];
    #pragma unroll
    for (int kt = 0; kt < 12; ++kt) {
        int row = (kt << 4) + lane16;
        int base = (row << 7) + (hi8 << 1);
        int swz = (row & 7) << 4;
        bf16x8 kf0 = *(const bf16x8*)(KsPs + (base ^ swz));
        bf16x8 kf1 = *(const bf16x8*)(KsPs + ((base + 64) ^ swz));
        floatx4 a = (floatx4){0.f,0.f,0.f,0.f};
        a = __builtin_amdgcn_mfma_f32_16x16x32_bf16(qf0, kf0, a, 0, 0, 0);
        a = __builtin_amdgcn_mfma_f32_16x16x32_bf16(qf1, kf1, a, 0, 0, 0);
        sc[kt] = a;
    }

    float inv_[4];
    #pragma unroll
    for (int r = 0; r < 4; ++r) {
        int qrow = q0 + (w << 4) + ((l >> 4) << 2) + r;
        float mx = -1e30f;
        #pragma unroll
        for (int kt = 0; kt < 12; ++kt) {
            int ks = kstart + (kt << 4) + lane16;
            int dd = qrow - ks; dd = dd < 0 ? -dd : dd;
            float sv = sc[kt][r] * 0.125f;
            sv = (dd <= 50 && ks < kend) ? sv : -1e30f;
            sc[kt][r] = sv;
            mx = fmaxf(mx, sv);
        }
        #pragma unroll
        for (int off = 1; off < 16; off <<= 1) mx = fmaxf(mx, __shfl_xor(mx, off));
        float sum = 0.f;
        #pragma unroll
        for (int kt = 0; kt < 12; ++kt) {
            float p = __expf(sc[kt][r] - mx);
            sc[kt][r] = p;
            sum += p;
        }
        #pragma unroll
        for (int off = 1; off < 16; off <<= 1) sum += __shfl_xor(sum, off);
        inv_[r] = 1.0f / sum;
    }

    __syncthreads();   // all waves done reading K window -> P may overwrite it

    // P -> per-wave LDS, swizzled writes
    char* PwB = KsPs + w * 6400;
    #pragma unroll
    for (int r = 0; r < 4; ++r) {
        int prow = ((l >> 4) << 2) + r;
        int pm = ((prow >> 2) & 3) << 4;
        #pragma unroll
        for (int kt = 0; kt < 12; ++kt) {
            int keyoff = ((kt << 4) + lane16) << 1;
            *(bf16_t*)(PwB + prow * 400 + (keyoff ^ pm)) = (bf16_t)(sc[kt][r] * inv_[r]);
        }
    }

    floatx4 oc[4];
    #pragma unroll
    for (int dt = 0; dt < 4; ++dt) oc[dt] = (floatx4){0.f,0.f,0.f,0.f};
    int pm_r = ((lane16 >> 2) & 3) << 4;
    #pragma unroll
    for (int ks = 0; ks < 6; ++ks) {
        int keyoff = ((ks << 5) + hi8) << 1;
        bf16x8 pf = *(const bf16x8*)(PwB + lane16 * 400 + (keyoff ^ pm_r));
        #pragma unroll
        for (int dt = 0; dt < 4; ++dt) {
            int d = (dt << 4) + lane16;
            bf16x8 vf = *(const bf16x8*)(VtB + d * 400 + (keyoff ^ (((d >> 3) & 7) << 4)));
            oc[dt] = __builtin_amdgcn_mfma_f32_16x16x32_bf16(pf, vf, oc[dt], 0, 0, 0);
        }
    }
    #pragma unroll
    for (int dt = 0; dt < 4; ++dt)
        #pragma unroll
        for (int r = 0; r < 4; ++r) {
            int qq = q0 + (w << 4) + ((l >> 4) << 2) + r;
            AO[(((size_t)(b_ * 2048 + qq)) << 10) + (h << 6) + (dt << 4) + lane16] = (bf16_t)oc[dt][r];
        }
}

extern "C" void kernel_launch(void* const* d_in, const int* in_sizes, int n_in,
                              void* d_out, int out_size, void* d_ws, size_t ws_size,
                              hipStream_t stream)
{
    const float* query = (const float*)d_in[0];
    const float* key_  = (const float*)d_in[1];
    const float* value = (const float*)d_in[2];
    const float* Wq = (const float*)d_in[3];
    const float* bq = (const float*)d_in[4];
    const float* Wk = (const float*)d_in[5];
    const float* bk = (const float*)d_in[6];
    const float* Wv = (const float*)d_in[7];
    const float* bv = (const float*)d_in[8];
    const float* Wo = (const float*)d_in[9];
    const float* bo = (const float*)d_in[10];

    char* ws = (char*)d_ws;
    bf16_t* Wqb = (bf16_t*)(ws);
    bf16_t* Wkb = (bf16_t*)(ws + 2097152);
    bf16_t* Wvb = (bf16_t*)(ws + 4194304);
    bf16_t* Wob = (bf16_t*)(ws + 6291456);
    bf16_t* Qr  = (bf16_t*)(ws + 8388608);
    bf16_t* Kr  = (bf16_t*)(ws + 16777216);
    bf16_t* Vh  = (bf16_t*)(ws + 25165824);
    bf16_t* AO  = (bf16_t*)(ws + 33554432);
    float*  ct  = (float*)(ws + 41943040);
    float*  st  = (float*)(ws + 42205184);

    k_prep<<<2304, 256, 0, stream>>>(Wq, Wk, Wv, Wo, Wqb, Wkb, Wvb, Wob, ct, st);
    k_gemm_qkv<<<768, 256, 0, stream>>>(query, key_, value, Wqb, Wkb, Wvb,
                                        bq, bk, bv, Qr, Kr, Vh, ct, st);
    k_attn<<<1024, 256, 0, stream>>>(Qr, Kr, Vh, AO);
    k_gemm_o<<<1024, 256, 0, stream>>>(AO, Wob, bo, (float*)d_out);
}